// Round 8
// baseline (292.774 us; speedup 1.0000x reference)
//
#include <hip/hip_runtime.h>
#include <math.h>

// Problem constants
#define BG   64      // graphs
#define NN   2048    // nodes per graph
#define DD   256     // hidden dim
#define CQ   16      // 12 class queries + 4 group queries fused
#define CN   128     // nodes per chunk
#define NCH  16      // chunks per graph (NN / CN)

// Workspace layout (in floats)
static constexpr size_t WS_Q16 = 0;                                  // [16][256]
static constexpr size_t WS_H   = 4096;                               // [4][512]
static constexpr size_t WS_S   = 6144;                               // scores [64][16][2048]
static constexpr size_t WS_ML  = WS_S + (size_t)BG * CQ * NN;        // [64*16][32] chunk m|l
static constexpr size_t WS_PL  = WS_ML + (size_t)BG * NCH * 32;      // pooled [64*16][16][256]

// ---------------------------------------------------------------------------
// A1: h[g][j] = relu(q[g] . w1[g][:,j] + b1[g][j]); copy group queries to
// Q16 rows 12..15.  grid 64 = 4 groups x 16 j-chunks of 32, block 256.
__global__ __launch_bounds__(256) void kA1(const float* __restrict__ gq,
                                           const float* __restrict__ w1,
                                           const float* __restrict__ b1,
                                           float* __restrict__ ws) {
    int blk = blockIdx.x;
    int g   = blk >> 4;
    int jb  = (blk & 15) * 32;
    int t   = threadIdx.x;
    __shared__ float qlds[256];
    qlds[t] = gq[g * 256 + t];
    if ((blk & 15) == 0) ws[WS_Q16 + (12 + g) * 256 + t] = gq[g * 256 + t];
    __syncthreads();
    int jl = t & 31, dp = t >> 5;              // 32 j x 8 d-parts
    float acc = 0.f;
    const float* wp = w1 + ((size_t)g * 256) * 512 + jb + jl;
    #pragma unroll 8
    for (int i = 0; i < 32; ++i) {
        int d = dp * 32 + i;
        acc += qlds[d] * wp[(size_t)d * 512];
    }
    __shared__ float red[8][33];
    red[dp][jl] = acc;
    __syncthreads();
    if (dp == 0) {
        float s = 0.f;
        #pragma unroll
        for (int p = 0; p < 8; ++p) s += red[p][jl];
        s += b1[g * 512 + jb + jl];
        ws[WS_H + g * 512 + jb + jl] = fmaxf(s, 0.f);
    }
}

// A2: flat[g][k] = h[g] . w2[g][:,k] + b2[g][k] -> Q16 rows 0..11.
// grid 192 = 4 groups x 48 k-chunks of 16, block 256 (16 k x 16 d-parts).
__global__ __launch_bounds__(256) void kA2(const float* __restrict__ w2,
                                           const float* __restrict__ b2,
                                           float* __restrict__ ws) {
    int blk = blockIdx.x;
    int g   = blk / 48;
    int kb  = (blk % 48) * 16;
    int t   = threadIdx.x;
    __shared__ float hlds[512];
    hlds[t]       = ws[WS_H + g * 512 + t];
    hlds[t + 256] = ws[WS_H + g * 512 + t + 256];
    __syncthreads();
    int kl = t & 15, dp = t >> 4;              // 16 k x 16 d-parts (32 each)
    float acc = 0.f;
    const float* wp = w2 + ((size_t)g * 512) * 768 + kb + kl;
    #pragma unroll 8
    for (int i = 0; i < 32; ++i) {
        int jj = dp * 32 + i;
        acc += hlds[jj] * wp[(size_t)jj * 768];
    }
    __shared__ float red[16][17];
    red[dp][kl] = acc;
    __syncthreads();
    if (dp == 0) {
        float s = 0.f;
        #pragma unroll
        for (int p = 0; p < 16; ++p) s += red[p][kl];
        ws[WS_Q16 + g * 768 + kb + kl] = s + b2[g * 768 + kb + kl];
    }
}

// ---------------------------------------------------------------------------
// F: fused scores + chunk-softmax-partials + chunk pooling.
// grid 1024 = (b, chunk of 128 nodes); block 256 (4 waves).
// Phase 1: 2 threads/node (D split in half); q16 via LDS broadcast; 8-deep
//          x prefetch; halves combined through wlds; raw scores -> ws.
// Phase 2: per-c chunk max & sumexp (LDS + 16-lane shfl).
// Phase 3: wave owns 32 nodes, lane owns float4 of D; x re-read (L2-hot);
//          exp-weights broadcast from LDS.  Emits (m,l) + pooled[16][256].
__global__ __launch_bounds__(256) void kF(const float* __restrict__ x,
                                          float* __restrict__ ws) {
    __shared__ float4 qlds[CQ * 64];           // 16 KB; reused as combine scratch
    __shared__ float  wlds[CQ * CN];           // 8 KB: partials -> scores -> exp-weights
    __shared__ float  mbuf[CQ], lbuf[CQ];

    int t   = threadIdx.x;
    int blk = blockIdx.x;
    int b   = blk >> 4, ch = blk & 15;
    int gn0 = b * NN + ch * CN;                // global node base of this chunk

    const float4* qg = (const float4*)(ws + WS_Q16);
    #pragma unroll
    for (int i = 0; i < 4; ++i) qlds[t + i * 256] = qg[t + i * 256];
    __syncthreads();

    // ---- Phase 1: scores, 2 threads per node (half = D/2 split) ----
    int nl = t & 127, half = t >> 7;
    const float4* xa = (const float4*)x + (size_t)(gn0 + nl) * 64 + half * 32;
    float sc[CQ];
    #pragma unroll
    for (int c = 0; c < CQ; ++c) sc[c] = 0.f;

    float4 buf[8];
    #pragma unroll
    for (int i = 0; i < 8; ++i) buf[i] = xa[i];
    for (int base = 0; base < 32; base += 8) {
        float4 cur[8];
        #pragma unroll
        for (int i = 0; i < 8; ++i) cur[i] = buf[i];
        if (base + 8 < 32) {
            #pragma unroll
            for (int i = 0; i < 8; ++i) buf[i] = xa[base + 8 + i];
        }
        #pragma unroll
        for (int i = 0; i < 8; ++i) {
            #pragma unroll
            for (int c = 0; c < CQ; ++c) {
                float4 q = qlds[c * 64 + half * 32 + base + i];
                sc[c] += q.x * cur[i].x + q.y * cur[i].y
                       + q.z * cur[i].z + q.w * cur[i].w;
            }
        }
    }
    if (half == 1) {
        #pragma unroll
        for (int c = 0; c < CQ; ++c) wlds[c * CN + nl] = sc[c];
    }
    __syncthreads();
    if (half == 0) {
        float* srow = ws + WS_S + ((size_t)b * CQ) * NN + ch * CN;
        #pragma unroll
        for (int c = 0; c < CQ; ++c) {
            float full = (sc[c] + wlds[c * CN + nl]) * 0.0625f;
            srow[(size_t)c * NN + nl] = full;   // raw score for attn output
            wlds[c * CN + nl] = full;
        }
    }
    __syncthreads();

    // ---- Phase 2: chunk max / sumexp per c (16 threads per c) ----
    {
        int c = t >> 4, slot = t & 15;
        float mv = -1e30f;
        #pragma unroll
        for (int k = 0; k < 8; ++k) mv = fmaxf(mv, wlds[c * CN + slot + k * 16]);
        #pragma unroll
        for (int off = 8; off; off >>= 1) mv = fmaxf(mv, __shfl_xor(mv, off, 16));
        if (slot == 0) mbuf[c] = mv;
    }
    __syncthreads();
    {
        int c = t >> 4, slot = t & 15;
        float m = mbuf[c];
        float lv = 0.f;
        #pragma unroll
        for (int k = 0; k < 8; ++k) {
            float e = __expf(wlds[c * CN + slot + k * 16] - m);
            wlds[c * CN + slot + k * 16] = e;
            lv += e;
        }
        #pragma unroll
        for (int off = 8; off; off >>= 1) lv += __shfl_xor(lv, off, 16);
        if (slot == 0) lbuf[c] = lv;
    }
    __syncthreads();
    if (t < CQ) {
        ws[WS_ML + (size_t)blk * 32 + t]      = mbuf[t];
        ws[WS_ML + (size_t)blk * 32 + 16 + t] = lbuf[t];
    }

    // ---- Phase 3: pooling (wave owns 32 nodes, lane owns float4 of D) ----
    int wave = t >> 6, lane = t & 63;
    float4 acc[CQ];
    #pragma unroll
    for (int c = 0; c < CQ; ++c) acc[c] = make_float4(0.f, 0.f, 0.f, 0.f);

    const float4* xq = (const float4*)x + (size_t)(gn0 + wave * 32) * 64 + lane;
    for (int nq = 0; nq < 8; ++nq) {           // node quads
        float4 x0 = xq[(size_t)(nq * 4 + 0) * 64];
        float4 x1 = xq[(size_t)(nq * 4 + 1) * 64];
        float4 x2 = xq[(size_t)(nq * 4 + 2) * 64];
        float4 x3 = xq[(size_t)(nq * 4 + 3) * 64];
        #pragma unroll
        for (int c = 0; c < CQ; ++c) {
            float4 ev = *(const float4*)&wlds[c * CN + wave * 32 + nq * 4];
            acc[c].x += ev.x * x0.x + ev.y * x1.x + ev.z * x2.x + ev.w * x3.x;
            acc[c].y += ev.x * x0.y + ev.y * x1.y + ev.z * x2.y + ev.w * x3.y;
            acc[c].z += ev.x * x0.z + ev.y * x1.z + ev.z * x2.z + ev.w * x3.z;
            acc[c].w += ev.x * x0.w + ev.y * x1.w + ev.z * x2.w + ev.w * x3.w;
        }
    }

    // cross-wave combine; qlds no longer needed -> reuse as scratch
    float* sdata = (float*)qlds;               // [16][256]
    for (int w = 0; w < 4; ++w) {
        if (wave == w) {
            #pragma unroll
            for (int c = 0; c < CQ; ++c) {
                float* dst = &sdata[c * 256 + lane * 4];
                if (w == 0) {
                    dst[0] = acc[c].x; dst[1] = acc[c].y;
                    dst[2] = acc[c].z; dst[3] = acc[c].w;
                } else {
                    dst[0] += acc[c].x; dst[1] += acc[c].y;
                    dst[2] += acc[c].z; dst[3] += acc[c].w;
                }
            }
        }
        __syncthreads();
    }
    float* po = ws + WS_PL + (size_t)blk * (CQ * 256);
    #pragma unroll
    for (int i = 0; i < CQ; ++i) po[t + i * 256] = sdata[t + i * 256];
}

// ---------------------------------------------------------------------------
// E: combine 16 chunk partials -> pooled row; LN; MLP -> logits; c<12 blocks
// also emit attn12 row = exp(s - m)/l.  grid 1024 = b*16+c, block 256.
__global__ __launch_bounds__(256) void kE(float* __restrict__ ws,
        const float* __restrict__ lnG12, const float* __restrict__ lnB12,
        const float* __restrict__ wA12,  const float* __restrict__ bA12,
        const float* __restrict__ wB12,  const float* __restrict__ bB12,
        const float* __restrict__ lnG4,  const float* __restrict__ lnB4,
        const float* __restrict__ wA4,   const float* __restrict__ bA4,
        const float* __restrict__ wB4,   const float* __restrict__ bB4,
        float* __restrict__ out, float* __restrict__ out_attn) {
    int bc = blockIdx.x;
    int b = bc >> 4, c = bc & 15;
    int t = threadIdx.x, wave = t >> 6, lane = t & 63;

    __shared__ float scl[NCH];
    __shared__ float smm, sil;
    if (t < NCH) {
        float mi = ws[WS_ML + (size_t)(b * NCH + t) * 32 + c];
        float li = ws[WS_ML + (size_t)(b * NCH + t) * 32 + 16 + c];
        float m = mi;
        #pragma unroll
        for (int off = 8; off; off >>= 1) m = fmaxf(m, __shfl_xor(m, off, 16));
        float sc = __expf(mi - m);
        float ls = sc * li;
        #pragma unroll
        for (int off = 8; off; off >>= 1) ls += __shfl_xor(ls, off, 16);
        scl[t] = sc;
        if (t == 0) { smm = m; sil = 1.f / ls; }
    }
    __syncthreads();
    float il = sil;

    float v = 0.f;
    #pragma unroll 4
    for (int i = 0; i < NCH; ++i)
        v += scl[i] * ws[WS_PL + ((size_t)(b * NCH + i) * CQ + c) * 256 + t];
    v *= il;

    __shared__ float wr1[4], wr2[4];
    float s = v;
    #pragma unroll
    for (int off = 32; off; off >>= 1) s += __shfl_xor(s, off, 64);
    if (lane == 0) wr1[wave] = s;
    __syncthreads();
    float mu = (wr1[0] + wr1[1] + wr1[2] + wr1[3]) * (1.f / 256.f);
    float dv = v - mu;
    s = dv * dv;
    #pragma unroll
    for (int off = 32; off; off >>= 1) s += __shfl_xor(s, off, 64);
    if (lane == 0) wr2[wave] = s;
    __syncthreads();
    float var = (wr2[0] + wr2[1] + wr2[2] + wr2[3]) * (1.f / 256.f);

    bool is12 = (c < 12);
    const float* lg = is12 ? lnG12 : lnG4;
    const float* lb = is12 ? lnB12 : lnB4;
    const float* wA = is12 ? wA12  : wA4;
    const float* bA = is12 ? bA12  : bA4;
    const float* wB = is12 ? wB12  : wB4;
    const float* bB = is12 ? bB12  : bB4;

    __shared__ float ylds[256];
    __shared__ float hred[256];
    __shared__ float hlds[128];
    float y = dv * rsqrtf(var + 1e-5f) * lg[t] + lb[t];
    ylds[t] = y;
    __syncthreads();
    {
        int j = t & 127, half = t >> 7;
        float hh = 0.f;
        const float* wc = wA + (size_t)half * 128 * 128 + j;
        #pragma unroll 4
        for (int d = 0; d < 128; ++d) hh += ylds[half * 128 + d] * wc[(size_t)d * 128];
        hred[t] = hh;
    }
    __syncthreads();
    if (t < 128) hlds[t] = fmaxf(hred[t] + hred[t + 128] + bA[t], 0.f);
    __syncthreads();
    if (t < 64) {
        float pp = hlds[t] * wB[t] + hlds[t + 64] * wB[t + 64];
        #pragma unroll
        for (int off = 32; off; off >>= 1) pp += __shfl_xor(pp, off, 64);
        if (t == 0) {
            float logit = pp + bB[0];
            if (is12) out[b * 12 + c] = logit;
            else      out[768 + b * 4 + (c - 12)] = logit;
        }
    }

    // attn12 row: exp(s - m) / l
    if (is12) {
        float m = smm;
        const float4* sr = (const float4*)(ws + WS_S + ((size_t)b * CQ + c) * NN);
        float4* ar = (float4*)out_attn + (size_t)(b * 12 + c) * (NN / 4);
        #pragma unroll
        for (int k = 0; k < 2; ++k) {
            float4 vv = sr[t + k * 256];
            float4 e;
            e.x = __expf(vv.x - m) * il;
            e.y = __expf(vv.y - m) * il;
            e.z = __expf(vv.z - m) * il;
            e.w = __expf(vv.w - m) * il;
            ar[t + k * 256] = e;
        }
    }
}

// ---------------------------------------------------------------------------
extern "C" void kernel_launch(void* const* d_in, const int* in_sizes, int n_in,
                              void* d_out, int out_size, void* d_ws, size_t ws_size,
                              hipStream_t stream) {
    const float* x     = (const float*)d_in[0];   // [131072, 256]
    const float* gq    = (const float*)d_in[2];   // [4, 256]
    const float* w1    = (const float*)d_in[3];   // [4, 256, 512]
    const float* b1    = (const float*)d_in[4];   // [4, 512]
    const float* w2    = (const float*)d_in[5];   // [4, 512, 768]
    const float* b2    = (const float*)d_in[6];   // [4, 768]
    const float* ln12g = (const float*)d_in[7];
    const float* ln12b = (const float*)d_in[8];
    const float* w12a  = (const float*)d_in[9];   // [256, 128]
    const float* b12a  = (const float*)d_in[10];
    const float* w12b  = (const float*)d_in[11];  // [128, 1]
    const float* b12b  = (const float*)d_in[12];
    const float* ln4g  = (const float*)d_in[13];
    const float* ln4b  = (const float*)d_in[14];
    const float* w4a   = (const float*)d_in[15];
    const float* b4a   = (const float*)d_in[16];
    const float* w4b   = (const float*)d_in[17];
    const float* b4b   = (const float*)d_in[18];

    float* out = (float*)d_out;               // [768 logits12][256 logits4][1572864 attn12]
    float* ws  = (float*)d_ws;

    kA1<<<64,       256, 0, stream>>>(gq, w1, b1, ws);
    kA2<<<192,      256, 0, stream>>>(w2, b2, ws);
    kF <<<BG * NCH, 256, 0, stream>>>(x, ws);
    kE <<<1024,     256, 0, stream>>>(ws,
            ln12g, ln12b, w12a, b12a, w12b, b12b,
            ln4g,  ln4b,  w4a,  b4a,  w4b,  b4b, out, out + 1024);
}